// Round 1
// baseline (109.534 us; speedup 1.0000x reference)
//
#include <hip/hip_runtime.h>

// Problem constants (from reference)
#define SEQLEN  128
#define NKV     8
#define BATCH   8
#define HD      128
#define MAXSEQ  4096

constexpr int       HD4     = HD / 4;                                   // 32 float4 per head row
constexpr long long HALF_F4 = (long long)BATCH * NKV * MAXSEQ * HD4;    // 8,388,608 float4 per output tensor

__global__ __launch_bounds__(256) void kv_update_kernel(
    const float4* __restrict__ xk,     // [SEQLEN][NKV][BATCH][HD]
    const float4* __restrict__ xv,
    const float4* __restrict__ kpast,  // [BATCH][NKV][MAXSEQ][HD]
    const float4* __restrict__ vpast,
    const int*    __restrict__ plen_ptr,
    float4*       __restrict__ out)    // new_k ++ new_v, flat
{
    const int plen = *plen_ptr;        // uniform address -> broadcast, cheap
    const long long total  = 2 * HALF_F4;
    const long long stride = (long long)gridDim.x * blockDim.x;

    for (long long i = (long long)blockIdx.x * blockDim.x + threadIdx.x;
         i < total; i += stride) {

        long long rem = i;
        const float4* past;
        const float4* xnew;
        if (rem >= HALF_F4) { rem -= HALF_F4; past = vpast; xnew = xv; }
        else                {                  past = kpast; xnew = xk; }

        // rem = ((b*NKV + h)*MAXSEQ + s)*HD4 + d4
        const int       d4  = (int)(rem & (HD4 - 1));      // % 32
        const long long row = rem >> 5;                    // / 32
        const int       s   = (int)(row & (MAXSEQ - 1));   // % 4096
        const int       bh  = (int)(row >> 12);            // / 4096
        const int       h   = bh & (NKV - 1);
        const int       b   = bh >> 3;

        const int sl = s - plen;
        float4 val;
        if ((unsigned)sl < (unsigned)SEQLEN) {
            // xk[sl][h][b][d]: flat float4 index = ((sl*NKV + h)*BATCH + b)*HD4 + d4
            val = xnew[(long long)((sl * NKV + h) * BATCH + b) * HD4 + d4];
        } else {
            val = past[rem];           // same flat offset -> perfectly coalesced
        }
        out[i] = val;
    }
}

extern "C" void kernel_launch(void* const* d_in, const int* in_sizes, int n_in,
                              void* d_out, int out_size, void* d_ws, size_t ws_size,
                              hipStream_t stream) {
    const float4* xk    = (const float4*)d_in[0];
    const float4* xv    = (const float4*)d_in[1];
    const float4* kpast = (const float4*)d_in[2];
    const float4* vpast = (const float4*)d_in[3];
    const int*    plen  = (const int*)d_in[4];
    float4*       out   = (float4*)d_out;

    dim3 grid(2048), block(256);   // grid-stride: ~32 float4 per thread
    kv_update_kernel<<<grid, block, 0, stream>>>(xk, xv, kpast, vpast, plen, out);
}